// Round 9
// baseline (2671.650 us; speedup 1.0000x reference)
//
#include <hip/hip_runtime.h>

// ---------------------------------------------------------------------------
// FusedSparseLMHead: weighted-mean CE over h @ W^T without materializing logits.
//   h: [4096, 2048] f32, W: [65536, 2048] f32, labels: [4096] int, w: [4096] f32
// Round 9: k-MAJOR LDS (unit = kc*256+row, 16B) -> 32x32 fragment reads are
//   consecutive-lane/consecutive-address = conflict-free (r5's 1e8 conflicts
//   were structural in row-major). Reg-staged A and B (T14 issue-early /
//   write-late), W fp32->bf16 fused in-kernel. ONE barrier + one lgkmcnt(0)
//   per K-tile; no vmcnt drains (compiler tracks reg deps). 32x32x16 MFMA,
//   static LDS offsets via t-unroll x2. 128 KB LDS, 8 waves, 1 block/CU.
// ---------------------------------------------------------------------------

typedef __attribute__((ext_vector_type(8)))  short bf16x8;
typedef __attribute__((ext_vector_type(16))) float f32x16;
typedef __attribute__((ext_vector_type(8)))  float f32x8;
typedef __attribute__((ext_vector_type(8)))  unsigned short u16x8;

#define N_TOK 4096
#define DIM   2048
#define VOCAB 65536
#define BM    256
#define BN    256
#define BK    64
#define NT    (DIM / BK)     // 32 K-tiles
#define NCH   (VOCAB / BN)   // 256 vocab chunks
#define NTB   (N_TOK / BM)   // 16 token blocks

__device__ __forceinline__ unsigned short f2bf(float x) {
    unsigned u = __float_as_uint(x);
    unsigned r = (u + 0x7fffu + ((u >> 16) & 1u)) >> 16;   // RNE
    return (unsigned short)r;
}

__device__ __forceinline__ void bar() {
    asm volatile("" ::: "memory");
    __builtin_amdgcn_s_barrier();
    asm volatile("" ::: "memory");
}

// ---------------------------------------------------------------- convert ---
__global__ __launch_bounds__(256) void convert_f32_bf16(
    const float* __restrict__ src, unsigned short* __restrict__ dst, long n)
{
    long i = ((long)blockIdx.x * 256 + threadIdx.x) * 8;
    if (i + 8 > n) return;
    f32x8 v = *(const f32x8*)(src + i);
    u16x8 o;
    #pragma unroll
    for (int j = 0; j < 8; ++j) o[j] = f2bf(v[j]);
    *(u16x8*)(dst + i) = o;
}

// ------------------------- k-major 256^2 GEMM+LSE, fused W convert ---------
__global__ __launch_bounds__(512, 2) void gemm_lse(
    const unsigned short* __restrict__ hA,    // [4096][2048] bf16 bits
    const float* __restrict__ Wf,             // [65536][2048] fp32
    float* __restrict__ part_m, float* __restrict__ part_s)
{
    // k-major: 16-B unit (kc, row) at unit index kc*256 + row; kc = k/8.
    __shared__ unsigned short A_lds[2][16384];   // 64 KB (2 x 256rows x 64k)
    __shared__ unsigned short B_lds[2][16384];   // 64 KB

    const int tid  = threadIdx.x;
    const int lane = tid & 63;
    const int w    = tid >> 6;       // wave 0..7
    const int wm   = w >> 2;         // 0..1 : token half (128 rows)
    const int wn   = w & 3;          // 0..3 : vocab quarter (64 cols)

    // XCD remap (nwg = 4096, multiple of 8): 16 consecutive wg (one vocab
    // chunk x 16 token blocks) land on one XCD -> W panel L2-resident.
    const int orig = blockIdx.x;
    const int wg   = (orig & 7) * 512 + (orig >> 3);
    const int tok_blk = wg & (NTB - 1);
    const int voc_blk = wg >> 4;

    const long arow0 = (long)tok_blk * BM;
    const unsigned short* Ab = hA + arow0 * DIM;
    const float* Wb = Wf + (long)voc_blk * BN * DIM;

    f32x16 acc[4][2];
    #pragma unroll
    for (int i = 0; i < 4; ++i)
        #pragma unroll
        for (int j = 0; j < 2; ++j)
            #pragma unroll
            for (int e = 0; e < 16; ++e)
                acc[i][j][e] = 0.f;

    // ---- staging map: thread covers row srow, kc in [sj4, sj4+4) ----------
    // (2 threads/row; each loads 64 B of A bf16 / 128 B of W fp32, contiguous)
    const int srow = tid >> 1;
    const int sj4  = (tid & 1) * 4;
    const unsigned short* Asrc = Ab + (long)srow * DIM + sj4 * 8;
    const float*          Bsrc = Wb + (long)srow * DIM + sj4 * 8;
    const int sdst = (sj4 * 256 + srow) * 8;     // shorts; + j*2048 per j
    // write banks: lanes pair (srow equal, sj4 0/4) -> same 16B-group = 2-way
    // aliasing (free, m136); within 8 lanes rows advance -> groups distinct.

#define STAGE_LOAD(t)                                                         \
    _Pragma("unroll")                                                         \
    for (int j = 0; j < 4; ++j) {                                             \
        areg[j] = *(const bf16x8*)(Asrc + (t) * BK + j * 8);                  \
        const float4* p = (const float4*)(Bsrc + (t) * BK + j * 8);           \
        br0[j] = p[0];                                                        \
        br1[j] = p[1];                                                        \
    }

#define STAGE_WRITE(NXT)                                                      \
    _Pragma("unroll")                                                         \
    for (int j = 0; j < 4; ++j)                                               \
        *(bf16x8*)(&A_lds[NXT][sdst + j * 2048]) = areg[j];                   \
    _Pragma("unroll")                                                         \
    for (int j = 0; j < 4; ++j) {                                             \
        u16x8 o;                                                              \
        o[0] = f2bf(br0[j].x); o[1] = f2bf(br0[j].y);                         \
        o[2] = f2bf(br0[j].z); o[3] = f2bf(br0[j].w);                         \
        o[4] = f2bf(br1[j].x); o[5] = f2bf(br1[j].y);                         \
        o[6] = f2bf(br1[j].z); o[7] = f2bf(br1[j].w);                         \
        *(u16x8*)(&B_lds[NXT][sdst + j * 2048]) = o;                          \
    }

    // ---- fragment read bases (bytes). unit byte = kc*4096 + row*16.
    // A row = wm*128 + q*32 + (lane&31); kc = kk*2 + (lane>>5):
    //   byte = kk*8192 + hk*4096 + wm*2048 + q*512 + rlane*16
    // lanes 0..31 -> consecutive 16-B units -> conflict-free ds_read_b128.
    const int rlane = lane & 31, hk = lane >> 5;
    const int abase = hk * 4096 + wm * 2048 + rlane * 16;
    const int bbase = hk * 4096 + wn * 1024 + rlane * 16;

// One K-tile, ONE barrier. WAR: tile t reads buf CUR (forced complete by MFMA
// deps before the barrier); writes go to buf NXT whose previous readers all
// passed the PREVIOUS barrier with reads complete. lgkmcnt(0) publishes the
// ds_writes; the "memory" clobber pins writes before it.
#define KSTEP(CUR, NXT, t)                                                    \
    {                                                                         \
        bf16x8 areg[4]; float4 br0[4], br1[4];                                \
        if ((t) + 1 < NT) { STAGE_LOAD((t) + 1) }                             \
        bf16x8 bfr[2][4];                                                     \
        _Pragma("unroll")                                                     \
        for (int nf = 0; nf < 2; ++nf)                                        \
            _Pragma("unroll")                                                 \
            for (int kk = 0; kk < 4; ++kk)                                    \
                bfr[nf][kk] = *(const bf16x8*)((const char*)&B_lds[CUR][0] +  \
                    bbase + kk * 8192 + nf * 512);                            \
        _Pragma("unroll")                                                     \
        for (int q = 0; q < 4; ++q) {                                         \
            bf16x8 afr[4];                                                    \
            _Pragma("unroll")                                                 \
            for (int kk = 0; kk < 4; ++kk)                                    \
                afr[kk] = *(const bf16x8*)((const char*)&A_lds[CUR][0] +      \
                    abase + kk * 8192 + q * 512);                             \
            __builtin_amdgcn_s_setprio(1);                                    \
            _Pragma("unroll")                                                 \
            for (int kk = 0; kk < 4; ++kk)                                    \
                _Pragma("unroll")                                             \
                for (int nf = 0; nf < 2; ++nf)                                \
                    acc[q][nf] = __builtin_amdgcn_mfma_f32_32x32x16_bf16(     \
                        afr[kk], bfr[nf][kk], acc[q][nf], 0, 0, 0);           \
            __builtin_amdgcn_s_setprio(0);                                    \
        }                                                                     \
        if ((t) + 1 < NT) { STAGE_WRITE(NXT) }                                \
        asm volatile("s_waitcnt lgkmcnt(0)" ::: "memory");                    \
        bar();                                                                \
    }

    // prologue: tile 0 -> buf 0
    {
        bf16x8 areg[4]; float4 br0[4], br1[4];
        STAGE_LOAD(0)
        STAGE_WRITE(0)
        asm volatile("s_waitcnt lgkmcnt(0)" ::: "memory");
        bar();
    }

    for (int t = 0; t < NT; t += 2) {
        KSTEP(0, 1, t)
        KSTEP(1, 0, t + 1)
    }
#undef KSTEP
#undef STAGE_LOAD
#undef STAGE_WRITE

    // ---- epilogue: per-token (max, sumexp) over this block's 256 cols ----
    // (r5-verified) 32x32 C/D: col = lane&31 (vocab), row = (rg&3) + 8*(rg>>2)
    // + 4*(lane>>5) (token). Reduce over 64 cols via nf-pair + 5 shfls.
    float* red_m = (float*)&A_lds[0][0];          // 4 KB
    float* red_s = ((float*)&A_lds[0][0]) + 1024; // 4 KB
    #pragma unroll
    for (int q = 0; q < 4; ++q) {
        #pragma unroll
        for (int rg = 0; rg < 16; ++rg) {
            float v0 = acc[q][0][rg], v1 = acc[q][1][rg];
            float mx = fmaxf(v0, v1);
            #pragma unroll
            for (int msk = 1; msk < 32; msk <<= 1)
                mx = fmaxf(mx, __shfl_xor(mx, msk, 64));
            float se = __expf(v0 - mx) + __expf(v1 - mx);
            #pragma unroll
            for (int msk = 1; msk < 32; msk <<= 1)
                se += __shfl_xor(se, msk, 64);
            if ((lane & 31) == 0) {
                const int row = wm * 128 + q * 32 + (rg & 3) + 8 * (rg >> 2) +
                                4 * (lane >> 5);
                red_m[row * 4 + wn] = mx;
                red_s[row * 4 + wn] = se;
            }
        }
    }
    __syncthreads();
    if (tid < 256) {
        float M = red_m[tid * 4], S = red_s[tid * 4];
        #pragma unroll
        for (int j = 1; j < 4; ++j) {
            const float m2 = red_m[tid * 4 + j], s2 = red_s[tid * 4 + j];
            const float Mn = fmaxf(M, m2);
            S = S * __expf(M - Mn) + s2 * __expf(m2 - Mn);
            M = Mn;
        }
        part_m[(arow0 + tid) * NCH + voc_blk] = M;
        part_s[(arow0 + tid) * NCH + voc_blk] = S;
    }
}

// ------------------------------------------------------- exact label dot ----
__global__ __launch_bounds__(256) void label_dot(
    const float* __restrict__ h, const float* __restrict__ W,
    const void* __restrict__ labels, float* __restrict__ lab_logit)
{
    bool is64 = true;
    #pragma unroll
    for (int i = 0; i < 8; ++i) {
        long long v = ((const long long*)labels)[i];
        if (v < 0 || v >= VOCAB) is64 = false;
    }
    const int t = blockIdx.x;
    const int lab = is64 ? (int)((const long long*)labels)[t]
                         : ((const int*)labels)[t];
    const float4* hp = (const float4*)(h + (long)t * DIM);
    const float4* wp = (const float4*)(W + (long)lab * DIM);
    float s = 0.f;
    #pragma unroll
    for (int j = 0; j < 2; ++j) {
        const float4 a = hp[threadIdx.x + j * 256];
        const float4 b = wp[threadIdx.x + j * 256];
        s += a.x * b.x + a.y * b.y + a.z * b.z + a.w * b.w;
    }
    #pragma unroll
    for (int msk = 1; msk < 64; msk <<= 1) s += __shfl_xor(s, msk, 64);
    __shared__ float ps[4];
    if ((threadIdx.x & 63) == 0) ps[threadIdx.x >> 6] = s;
    __syncthreads();
    if (threadIdx.x == 0) lab_logit[t] = ps[0] + ps[1] + ps[2] + ps[3];
}

// ---------------------------------------------------- per-token LSE merge ---
__global__ __launch_bounds__(256) void finalize_nll(
    const float* __restrict__ part_m, const float* __restrict__ part_s,
    const float* __restrict__ lab_logit, const float* __restrict__ wts,
    float* __restrict__ wnll)
{
    const int t    = blockIdx.x * 4 + (threadIdx.x >> 6);  // one wave / token
    const int lane = threadIdx.x & 63;
    float m = -3.4e38f, s = 0.f;
    #pragma unroll
    for (int j = 0; j < 4; ++j) {
        const int c = j * 64 + lane;
        const float pm = part_m[(long)t * NCH + c];
        const float ps = part_s[(long)t * NCH + c];
        const float M = fmaxf(m, pm);
        s = s * __expf(m - M) + ps * __expf(pm - M);
        m = M;
    }
    #pragma unroll
    for (int msk = 1; msk < 64; msk <<= 1) {
        const float om = __shfl_xor(m, msk, 64);
        const float os = __shfl_xor(s, msk, 64);
        const float M = fmaxf(m, om);
        s = s * __expf(m - M) + os * __expf(om - M);
        m = M;
    }
    if (lane == 0) {
        const float lse = m + logf(s);
        wnll[t] = wts[t] * (lse - lab_logit[t]);
    }
}

// -------------------------------------------------- deterministic reduce ----
__global__ __launch_bounds__(1024) void final_reduce(
    const float* __restrict__ wnll, const float* __restrict__ wts,
    float* __restrict__ out)
{
    float a = 0.f, b = 0.f;
    #pragma unroll
    for (int j = 0; j < 4; ++j) {
        const int i = threadIdx.x + j * 1024;
        a += wnll[i];
        b += wts[i];
    }
    #pragma unroll
    for (int msk = 1; msk < 64; msk <<= 1) {
        a += __shfl_xor(a, msk, 64);
        b += __shfl_xor(b, msk, 64);
    }
    __shared__ float pa[16], pb[16];
    if ((threadIdx.x & 63) == 0) {
        pa[threadIdx.x >> 6] = a;
        pb[threadIdx.x >> 6] = b;
    }
    __syncthreads();
    if (threadIdx.x == 0) {
        float A = 0.f, B = 0.f;
        #pragma unroll
        for (int i = 0; i < 16; ++i) { A += pa[i]; B += pb[i]; }
        out[0] = A / B;
    }
}

// ----------------------------------------------------------------- launch ---
extern "C" void kernel_launch(void* const* d_in, const int* in_sizes, int n_in,
                              void* d_out, int out_size, void* d_ws, size_t ws_size,
                              hipStream_t stream)
{
    const float* h      = (const float*)d_in[0];
    const void*  labels = d_in[1];
    const float* wts    = (const float*)d_in[2];
    const float* W      = (const float*)d_in[3];
    float* out = (float*)d_out;

    char* ws = (char*)d_ws;
    unsigned short* h_bf      = (unsigned short*)(ws);                 // 16 MB
    float*          part_m    = (float*)(ws + (16u << 20));            //  4 MB
    float*          part_s    = (float*)(ws + (24u << 20));            //  4 MB
    float*          lab_logit = (float*)(ws + (32u << 20));            // 16 KB
    float*          wnll      = (float*)(ws + (32u << 20) + 16384);    // 16 KB

    // 0) h -> bf16 (W converts inside the GEMM)
    convert_f32_bf16<<<(N_TOK * DIM) / (256 * 8), 256, 0, stream>>>(
        h, h_bf, (long)N_TOK * DIM);

    // 1) single fused GEMM/convert/LSE launch over the whole vocab
    gemm_lse<<<NTB * NCH, 512, 0, stream>>>(h_bf, W, part_m, part_s);

    // 2) exact label logits (fp32)
    label_dot<<<N_TOK, 256, 0, stream>>>(h, W, labels, lab_logit);

    // 3) per-token LSE merge -> w*nll
    finalize_nll<<<N_TOK / 4, 256, 0, stream>>>(part_m, part_s, lab_logit,
                                                wts, wnll);

    // 4) weighted mean
    final_reduce<<<1, 1024, 0, stream>>>(wnll, wts, out);
}

// Round 10
// 1320.367 us; speedup vs baseline: 2.0234x; 2.0234x over previous
//
#include <hip/hip_runtime.h>

// ---------------------------------------------------------------------------
// FusedSparseLMHead: weighted-mean CE over h @ W^T without materializing logits.
//   h: [4096, 2048] f32, W: [65536, 2048] f32, labels: [4096] int, w: [4096] f32
// Round 10: 256x256 tile, BK=32, 4-slot LDS ring (128 KB), gload_lds both
//   operands (no reg staging -> no spill), 16x16x32 MFMA with the r8-measured
//   0-conflict 16-row pattern (64-B rows, chunk swizzle c^(r&3)).
//   Schedule (m201 mechanism: MFMA fire-and-forget past barriers):
//     PH1: stage A(t+2) | 4 B-frag + 4 A-frag reads | bar | lgkm(0) | 16 MFMA
//     PH2: stage B(t+2) | 4 A-frag reads            | bar | lgkm(0) | 16 MFMA
//          | vmcnt(4) | bar        <- counted, NEVER 0 in the loop
//   RAW: vmcnt(4) at end of t forces tile t+1 landed (only t+2's 4 float).
//   WAR: slot (t+2)&3 last read in step t-2, whose reads complete before its
//        own MFMAs/lgkm; writes for t+2 issue in step t (after t-1's barrier).
// ---------------------------------------------------------------------------

typedef __attribute__((ext_vector_type(8)))  short bf16x8;
typedef __attribute__((ext_vector_type(4)))  float f32x4;
typedef __attribute__((ext_vector_type(8)))  float f32x8;
typedef __attribute__((ext_vector_type(8)))  unsigned short u16x8;

#define N_TOK 4096
#define DIM   2048
#define VOCAB 65536
#define BM    256
#define BN    256
#define BK    32
#define NT    (DIM / BK)     // 64 K-steps
#define NCH   (VOCAB / BN)   // 256 vocab chunks
#define NTB   (N_TOK / BM)   // 16 token blocks

__device__ __forceinline__ unsigned short f2bf(float x) {
    unsigned u = __float_as_uint(x);
    unsigned r = (u + 0x7fffu + ((u >> 16) & 1u)) >> 16;   // RNE
    return (unsigned short)r;
}

__device__ __forceinline__ void gload_lds16(const void* g, void* l) {
    __builtin_amdgcn_global_load_lds(
        (const __attribute__((address_space(1))) void*)g,
        (__attribute__((address_space(3))) void*)l, 16, 0, 0);
}

__device__ __forceinline__ void bar() {
    asm volatile("" ::: "memory");
    __builtin_amdgcn_s_barrier();
    asm volatile("" ::: "memory");
}

// ---------------------------------------------------------------- convert ---
__global__ __launch_bounds__(256) void convert_f32_bf16(
    const float* __restrict__ src, unsigned short* __restrict__ dst, long n)
{
    long i = ((long)blockIdx.x * 256 + threadIdx.x) * 8;
    if (i + 8 > n) return;
    f32x8 v = *(const f32x8*)(src + i);
    u16x8 o;
    #pragma unroll
    for (int j = 0; j < 8; ++j) o[j] = f2bf(v[j]);
    *(u16x8*)(dst + i) = o;
}

// -------------------------- 256^2 BK=32 ring GEMM+LSE (counted vmcnt) ------
__global__ __launch_bounds__(512, 2) void gemm_lse(
    const unsigned short* __restrict__ hA,    // [4096][2048] bf16 bits
    const unsigned short* __restrict__ Wb,    // [seg_rows][2048] bf16 bits
    float* __restrict__ part_m, float* __restrict__ part_s, int chunk0)
{
    __shared__ unsigned short A_lds[4][8192];   // 4 x 16 KB (256r x 32k)
    __shared__ unsigned short B_lds[4][8192];   // 4 x 16 KB

    const int tid  = threadIdx.x;
    const int lane = tid & 63;
    const int w    = tid >> 6;       // wave 0..7
    const int wm   = w >> 2;         // 0..1 : token half (128 rows)
    const int wn   = w & 3;          // 0..3 : vocab quarter (64 cols)

    // bijective XCD-aware remap, token-fastest decode
    const int nwg  = gridDim.x;
    const int orig = blockIdx.x;
    const int q8 = nwg >> 3, r8 = nwg & 7;
    const int xcd = orig & 7;
    const int wg  = (xcd < r8 ? xcd * (q8 + 1) : r8 * (q8 + 1) + (xcd - r8) * q8)
                    + (orig >> 3);
    const int tok_blk = wg & (NTB - 1);
    const int voc_blk = wg >> 4;                 // NTB == 16

    const long arow0 = (long)tok_blk * BM;
    const unsigned short* Ab = hA + arow0 * DIM;
    const unsigned short* Bb = Wb + (long)voc_blk * BN * DIM;

    f32x4 acc[8][4];
    #pragma unroll
    for (int i = 0; i < 8; ++i)
        #pragma unroll
        for (int j = 0; j < 4; ++j)
            acc[i][j] = (f32x4){0.f, 0.f, 0.f, 0.f};

    // ---- staging map: tile = 256 rows x 32 cols bf16 = 1024 16-B chunks,
    // 2 chunks/thread/operand. idx = j*512 + tid: r = idx>>2, c = idx&3.
    // LDS[r][c] = G[r][c ^ (r&3)] via pre-swizzled source + linear dest.
    // (rr+128)&3 == rr&3, so chunk j=1 shares the XOR.
    const int rr  = tid >> 2;
    const int cc  = tid & 3;
    const long aso = (long)rr * DIM + (cc ^ (rr & 3)) * 8;   // elements
    const int  db0 = (w * 64) * 16;                          // bytes (uniform)
    const int  db1 = (512 + w * 64) * 16;

#define STAGE_A(S2, t)                                                        \
    gload_lds16(Ab + (t) * BK + aso,             (char*)&A_lds[S2][0] + db0); \
    gload_lds16(Ab + (t) * BK + aso + 128 * DIM, (char*)&A_lds[S2][0] + db1);
#define STAGE_B(S2, t)                                                        \
    gload_lds16(Bb + (t) * BK + aso,             (char*)&B_lds[S2][0] + db0); \
    gload_lds16(Bb + (t) * BK + aso + 128 * DIM, (char*)&B_lds[S2][0] + db1);

    // ---- fragment read base (bytes). Row = 64 B = 4 chunks; global K-chunk
    // cc = lane>>4 read at LDS chunk cc ^ (row&3); row&3 == lane&3 (bases are
    // multiples of 16). Distinctness: u = r*4 + (c^(r&3)) covers 0..63 once,
    // u&7 balanced 8/group -> minimal 8 bank-cycles = conflict-free (r8: 0).
    const int rb = (lane & 15) * 64 + (((lane >> 4) ^ (lane & 3)) << 4);

#define LDB4(S)                                                               \
    _Pragma("unroll")                                                         \
    for (int n = 0; n < 4; ++n)                                               \
        bfr[n] = *(const bf16x8*)((const char*)&B_lds[S][0] +                 \
                                  wn * 4096 + n * 1024 + rb);
#define LDA4(DST, S, M0)                                                      \
    _Pragma("unroll")                                                         \
    for (int m = 0; m < 4; ++m)                                               \
        DST[m] = *(const bf16x8*)((const char*)&A_lds[S][0] +                 \
                                  wm * 8192 + ((M0) + m) * 1024 + rb);

#define MFMA16(AF, M0)                                                        \
    __builtin_amdgcn_s_setprio(1);                                            \
    _Pragma("unroll")                                                         \
    for (int m = 0; m < 4; ++m)                                               \
        _Pragma("unroll")                                                     \
        for (int n = 0; n < 4; ++n)                                           \
            acc[(M0) + m][n] = __builtin_amdgcn_mfma_f32_16x16x32_bf16(       \
                AF[m], bfr[n], acc[(M0) + m][n], 0, 0, 0);                    \
    __builtin_amdgcn_s_setprio(0);

#define KSTEP(S, S2, t)                                                       \
    {                                                                         \
        bf16x8 bfr[4], af1[4], af2[4];                                        \
        if ((t) + 2 < NT) { STAGE_A(S2, (t) + 2) }                            \
        LDB4(S)                                                               \
        LDA4(af1, S, 0)                                                       \
        bar();                                                                \
        asm volatile("s_waitcnt lgkmcnt(0)" ::: "memory");                    \
        __builtin_amdgcn_sched_barrier(0);                                    \
        MFMA16(af1, 0)                                                        \
        if ((t) + 2 < NT) { STAGE_B(S2, (t) + 2) }                            \
        LDA4(af2, S, 4)                                                       \
        bar();                                                                \
        asm volatile("s_waitcnt lgkmcnt(0)" ::: "memory");                    \
        __builtin_amdgcn_sched_barrier(0);                                    \
        MFMA16(af2, 4)                                                        \
        asm volatile("s_waitcnt vmcnt(4)" ::: "memory");                      \
        bar();                                                                \
    }

    // prologue: tiles 0,1 -> slots 0,1; vmcnt(4) = tile 0 landed (tile 1 floats
    // until the end-of-step-0 vmcnt(4)).
    STAGE_A(0, 0) STAGE_B(0, 0)
    STAGE_A(1, 1) STAGE_B(1, 1)
    asm volatile("s_waitcnt vmcnt(4)" ::: "memory");
    bar();

    for (int t = 0; t < NT; t += 4) {
        KSTEP(0, 2, t)
        KSTEP(1, 3, t + 1)
        KSTEP(2, 0, t + 2)
        KSTEP(3, 1, t + 3)
    }
#undef KSTEP
#undef STAGE_A
#undef STAGE_B
#undef LDA4
#undef LDB4
#undef MFMA16

    // ---- epilogue: per-token (max, sumexp) over this block's 256 cols ----
    // C frag (r4/r8-verified): row = wm*128 + mf*16 + (lane>>4)*4 + r,
    // col = wn*64 + nf*16 + (lane&15). 16-wide shfl only (measured 0-conflict).
    float* red_m = (float*)&A_lds[0][0];          // 4 KB
    float* red_s = ((float*)&A_lds[0][0]) + 1024; // 4 KB
    #pragma unroll
    for (int mf = 0; mf < 8; ++mf) {
        #pragma unroll
        for (int r = 0; r < 4; ++r) {
            float v0 = acc[mf][0][r], v1 = acc[mf][1][r];
            float v2 = acc[mf][2][r], v3 = acc[mf][3][r];
            float mx = fmaxf(fmaxf(v0, v1), fmaxf(v2, v3));
            #pragma unroll
            for (int msk = 1; msk < 16; msk <<= 1)
                mx = fmaxf(mx, __shfl_xor(mx, msk, 64));
            float se = __expf(v0 - mx) + __expf(v1 - mx) +
                       __expf(v2 - mx) + __expf(v3 - mx);
            #pragma unroll
            for (int msk = 1; msk < 16; msk <<= 1)
                se += __shfl_xor(se, msk, 64);
            if ((lane & 15) == 0) {
                const int row = wm * 128 + mf * 16 + (lane >> 4) * 4 + r;
                red_m[row * 4 + wn] = mx;
                red_s[row * 4 + wn] = se;
            }
        }
    }
    __syncthreads();
    if (tid < 256) {
        float M = red_m[tid * 4], S = red_s[tid * 4];
        #pragma unroll
        for (int j = 1; j < 4; ++j) {
            const float m2 = red_m[tid * 4 + j], s2 = red_s[tid * 4 + j];
            const float Mn = fmaxf(M, m2);
            S = S * __expf(M - Mn) + s2 * __expf(m2 - Mn);
            M = Mn;
        }
        part_m[(arow0 + tid) * NCH + chunk0 + voc_blk] = M;
        part_s[(arow0 + tid) * NCH + chunk0 + voc_blk] = S;
    }
}

// ------------------------------------------------------- exact label dot ----
__global__ __launch_bounds__(256) void label_dot(
    const float* __restrict__ h, const float* __restrict__ W,
    const void* __restrict__ labels, float* __restrict__ lab_logit)
{
    bool is64 = true;
    #pragma unroll
    for (int i = 0; i < 8; ++i) {
        long long v = ((const long long*)labels)[i];
        if (v < 0 || v >= VOCAB) is64 = false;
    }
    const int t = blockIdx.x;
    const int lab = is64 ? (int)((const long long*)labels)[t]
                         : ((const int*)labels)[t];
    const float4* hp = (const float4*)(h + (long)t * DIM);
    const float4* wp = (const float4*)(W + (long)lab * DIM);
    float s = 0.f;
    #pragma unroll
    for (int j = 0; j < 2; ++j) {
        const float4 a = hp[threadIdx.x + j * 256];
        const float4 b = wp[threadIdx.x + j * 256];
        s += a.x * b.x + a.y * b.y + a.z * b.z + a.w * b.w;
    }
    #pragma unroll
    for (int msk = 1; msk < 64; msk <<= 1) s += __shfl_xor(s, msk, 64);
    __shared__ float ps[4];
    if ((threadIdx.x & 63) == 0) ps[threadIdx.x >> 6] = s;
    __syncthreads();
    if (threadIdx.x == 0) lab_logit[t] = ps[0] + ps[1] + ps[2] + ps[3];
}

// ---------------------------------------------------- per-token LSE merge ---
__global__ __launch_bounds__(256) void finalize_nll(
    const float* __restrict__ part_m, const float* __restrict__ part_s,
    const float* __restrict__ lab_logit, const float* __restrict__ wts,
    float* __restrict__ wnll)
{
    const int t    = blockIdx.x * 4 + (threadIdx.x >> 6);  // one wave / token
    const int lane = threadIdx.x & 63;
    float m = -3.4e38f, s = 0.f;
    #pragma unroll
    for (int j = 0; j < 4; ++j) {
        const int c = j * 64 + lane;
        const float pm = part_m[(long)t * NCH + c];
        const float ps = part_s[(long)t * NCH + c];
        const float M = fmaxf(m, pm);
        s = s * __expf(m - M) + ps * __expf(pm - M);
        m = M;
    }
    #pragma unroll
    for (int msk = 1; msk < 64; msk <<= 1) {
        const float om = __shfl_xor(m, msk, 64);
        const float os = __shfl_xor(s, msk, 64);
        const float M = fmaxf(m, om);
        s = s * __expf(m - M) + os * __expf(om - M);
        m = M;
    }
    if (lane == 0) {
        const float lse = m + logf(s);
        wnll[t] = wts[t] * (lse - lab_logit[t]);
    }
}

// -------------------------------------------------- deterministic reduce ----
__global__ __launch_bounds__(1024) void final_reduce(
    const float* __restrict__ wnll, const float* __restrict__ wts,
    float* __restrict__ out)
{
    float a = 0.f, b = 0.f;
    #pragma unroll
    for (int j = 0; j < 4; ++j) {
        const int i = threadIdx.x + j * 1024;
        a += wnll[i];
        b += wts[i];
    }
    #pragma unroll
    for (int msk = 1; msk < 64; msk <<= 1) {
        a += __shfl_xor(a, msk, 64);
        b += __shfl_xor(b, msk, 64);
    }
    __shared__ float pa[16], pb[16];
    if ((threadIdx.x & 63) == 0) {
        pa[threadIdx.x >> 6] = a;
        pb[threadIdx.x >> 6] = b;
    }
    __syncthreads();
    if (threadIdx.x == 0) {
        float A = 0.f, B = 0.f;
        #pragma unroll
        for (int i = 0; i < 16; ++i) { A += pa[i]; B += pb[i]; }
        out[0] = A / B;
    }
}

// ----------------------------------------------------------------- launch ---
extern "C" void kernel_launch(void* const* d_in, const int* in_sizes, int n_in,
                              void* d_out, int out_size, void* d_ws, size_t ws_size,
                              hipStream_t stream)
{
    const float* h      = (const float*)d_in[0];
    const void*  labels = d_in[1];
    const float* wts    = (const float*)d_in[2];
    const float* W      = (const float*)d_in[3];
    float* out = (float*)d_out;

    char* ws = (char*)d_ws;
    unsigned short* h_bf      = (unsigned short*)(ws);                 // 16 MB
    float*          part_m    = (float*)(ws + (16u << 20));            //  4 MB
    float*          part_s    = (float*)(ws + (24u << 20));            //  4 MB
    float*          lab_logit = (float*)(ws + (32u << 20));            // 16 KB
    float*          wnll      = (float*)(ws + (32u << 20) + 16384);    // 16 KB
    unsigned short* wseg      = (unsigned short*)(ws + (32u << 20) + 32768);
    const size_t base = (size_t)(32u << 20) + 32768;

    long segmax = 0;
    if (ws_size > base) segmax = (long)((ws_size - base) / ((size_t)DIM * 2));
    segmax &= ~255L;
    if (segmax > VOCAB) segmax = VOCAB;
    if (segmax < 256)   segmax = 256;   // require ws_size >= ~34 MB

    // 0) h -> bf16
    convert_f32_bf16<<<(N_TOK * DIM) / (256 * 8), 256, 0, stream>>>(
        h, h_bf, (long)N_TOK * DIM);

    // 1) segmented W conversion + fused GEMM/LSE partials
    for (long v0 = 0; v0 < VOCAB; v0 += segmax) {
        const long rows = (VOCAB - v0) < segmax ? (VOCAB - v0) : segmax;
        convert_f32_bf16<<<(int)(rows * DIM / (256 * 8)), 256, 0, stream>>>(
            W + v0 * DIM, wseg, rows * (long)DIM);
        const int nwg = (int)(rows / BM) * NTB;
        gemm_lse<<<nwg, 512, 0, stream>>>(h_bf, wseg, part_m, part_s,
                                          (int)(v0 / BN));
    }

    // 2) exact label logits (fp32)
    label_dot<<<N_TOK, 256, 0, stream>>>(h, W, labels, lab_logit);

    // 3) per-token LSE merge -> w*nll
    finalize_nll<<<N_TOK / 4, 256, 0, stream>>>(part_m, part_s, lab_logit,
                                                wts, wnll);

    // 4) weighted mean
    final_reduce<<<1, 1024, 0, stream>>>(wnll, wts, out);
}

// Round 11
// 1286.621 us; speedup vs baseline: 2.0765x; 1.0262x over previous
//
#include <hip/hip_runtime.h>

// ---------------------------------------------------------------------------
// FusedSparseLMHead: weighted-mean CE over h @ W^T without materializing logits.
//   h: [4096, 2048] f32, W: [65536, 2048] f32, labels: [4096] int, w: [4096] f32
// Round 11: m201-style 8-phase 256^2 GEMM. BK=64, 16x16x32 MFMA.
//   LDS: A/B each 4 half-tile slots [parity*2+half][128x64] = 128 KB.
//   Layout (r8, measured 0-conflict): 128-B rows, LDS[r][c] = G[r][c^(r&7)]
//   (pre-swizzled gload source, linear dest; read XOR (lane&7)<<4).
//   Per K-tile, 4 phases; phase q: {LDA quadrant q (+LDB 8 in q0) | stage one
//   half-tile (A0,A1 of t+1; B0,B1 of t+2) | bar | lgkmcnt(0) | sched_barrier
//   | setprio(1) 16 MFMA setprio(0) | bar}; boundary vmcnt(4) -- counted,
//   never 0 until the last 2 tiles. Fully static slots (t+=2 unroll).
//   Queue proof (2 loads per half-tile stage): end of tile t queue =
//   [B(t+1)?, A(t+1) 4, B(t+2) 4]; vmcnt(4) forces everything except B(t+2)
//   -> A(t+1), B(t+1) landed for t+1; B(t+2) floats one more tile.
//   WAR: A[Pn] last read in t-1 (pre-barrier); B[P] read only in ph0 of t,
//   restaged in ph2/ph3 (separated by ph0/ph1 barriers).
// ---------------------------------------------------------------------------

typedef __attribute__((ext_vector_type(8)))  short bf16x8;
typedef __attribute__((ext_vector_type(4)))  float f32x4;
typedef __attribute__((ext_vector_type(8)))  float f32x8;
typedef __attribute__((ext_vector_type(8)))  unsigned short u16x8;

#define N_TOK 4096
#define DIM   2048
#define VOCAB 65536
#define BM    256
#define BN    256
#define BK    64
#define NT    (DIM / BK)     // 32 K-tiles
#define NCH   (VOCAB / BN)   // 256 vocab chunks
#define NTB   (N_TOK / BM)   // 16 token blocks

__device__ __forceinline__ unsigned short f2bf(float x) {
    unsigned u = __float_as_uint(x);
    unsigned r = (u + 0x7fffu + ((u >> 16) & 1u)) >> 16;   // RNE
    return (unsigned short)r;
}

__device__ __forceinline__ void gload_lds16(const void* g, void* l) {
    __builtin_amdgcn_global_load_lds(
        (const __attribute__((address_space(1))) void*)g,
        (__attribute__((address_space(3))) void*)l, 16, 0, 0);
}

__device__ __forceinline__ void bar() {
    asm volatile("" ::: "memory");
    __builtin_amdgcn_s_barrier();
    asm volatile("" ::: "memory");
}

// ---------------------------------------------------------------- convert ---
__global__ __launch_bounds__(256) void convert_f32_bf16(
    const float* __restrict__ src, unsigned short* __restrict__ dst, long n)
{
    long i = ((long)blockIdx.x * 256 + threadIdx.x) * 8;
    if (i + 8 > n) return;
    f32x8 v = *(const f32x8*)(src + i);
    u16x8 o;
    #pragma unroll
    for (int j = 0; j < 8; ++j) o[j] = f2bf(v[j]);
    *(u16x8*)(dst + i) = o;
}

// ----------------------------- m201-style 8-phase 256^2 GEMM+LSE -----------
__global__ __launch_bounds__(512, 2) void gemm_lse(
    const unsigned short* __restrict__ hA,    // [4096][2048] bf16 bits
    const unsigned short* __restrict__ Wb,    // [seg_rows][2048] bf16 bits
    float* __restrict__ part_m, float* __restrict__ part_s, int chunk0)
{
    __shared__ unsigned short A_lds[4][8192];   // [par*2+half][128x64] 64 KB
    __shared__ unsigned short B_lds[4][8192];   // 64 KB

    const int tid  = threadIdx.x;
    const int lane = tid & 63;
    const int w    = tid >> 6;       // wave 0..7
    const int wm   = w >> 2;         // 0..1 : token half (128 rows)
    const int wn   = w & 3;          // 0..3 : vocab quarter (64 cols)

    // bijective XCD-aware remap, token-fastest decode
    const int nwg  = gridDim.x;
    const int orig = blockIdx.x;
    const int q8 = nwg >> 3, r8 = nwg & 7;
    const int xcd = orig & 7;
    const int wg  = (xcd < r8 ? xcd * (q8 + 1) : r8 * (q8 + 1) + (xcd - r8) * q8)
                    + (orig >> 3);
    const int tok_blk = wg & (NTB - 1);
    const int voc_blk = wg >> 4;                 // NTB == 16

    const long arow0 = (long)tok_blk * BM;
    const unsigned short* Ab = hA + arow0 * DIM;
    const unsigned short* Bb = Wb + (long)voc_blk * BN * DIM;

    f32x4 acc[8][4];
    #pragma unroll
    for (int i = 0; i < 8; ++i)
        #pragma unroll
        for (int j = 0; j < 4; ++j)
            acc[i][j] = (f32x4){0.f, 0.f, 0.f, 0.f};

    // ---- staging map: half-tile = 128 rows x 8 chunks(16B); 2 loads/thread.
    // j in {0,1}: r = j*64 + w*8 + (lane>>3), c = lane&7; src chunk c^(r&7);
    // dest (wave-uniform base + lane*16) = linear -> LDS[r][c] = G[r][c^(r&7)].
    const int r0 = w * 8 + (lane >> 3);
    const int c0 = lane & 7;
    const long soff0 = (long)r0 * DIM + (c0 ^ (r0 & 7)) * 8;
    const long soff1 = (long)(r0 + 64) * DIM + (c0 ^ ((r0 + 64) & 7)) * 8;
    const int  sdb0  = (w * 64) * 16;
    const int  sdb1  = (512 + w * 64) * 16;

#define STAGE(GB, LB)                                                         \
    gload_lds16((GB) + soff0, (char*)(LB) + sdb0);                            \
    gload_lds16((GB) + soff1, (char*)(LB) + sdb1);

    // ---- fragment read addressing (r8 pattern, measured 0-conflict) ------
    const int rbA = (lane & 15) * 128;
    const int cx0 = ((lane >> 4) * 16) ^ ((lane & 7) << 4);        // kk = 0
    const int cx1 = (64 + (lane >> 4) * 16) ^ ((lane & 7) << 4);   // kk = 1
    const int brow = (wn & 1) * 64 * 128;

#define LDB8(BH)                                                              \
    _Pragma("unroll")                                                         \
    for (int nf = 0; nf < 4; ++nf) {                                          \
        bfr[nf][0] = *(const bf16x8*)((BH) + brow + nf * 2048 + rbA + cx0);   \
        bfr[nf][1] = *(const bf16x8*)((BH) + brow + nf * 2048 + rbA + cx1);   \
    }

#define LDA4(DST, AH, Q)                                                      \
    _Pragma("unroll")                                                         \
    for (int f = 0; f < 2; ++f) {                                             \
        DST[f][0] = *(const bf16x8*)((AH) + (Q) * 4096 + f * 2048 + rbA + cx0);\
        DST[f][1] = *(const bf16x8*)((AH) + (Q) * 4096 + f * 2048 + rbA + cx1);\
    }

#define MFMA16(AF, Q)                                                         \
    __builtin_amdgcn_s_setprio(1);                                            \
    _Pragma("unroll")                                                         \
    for (int kk = 0; kk < 2; ++kk)                                            \
        _Pragma("unroll")                                                     \
        for (int f = 0; f < 2; ++f)                                           \
            _Pragma("unroll")                                                 \
            for (int nf = 0; nf < 4; ++nf)                                    \
                acc[(Q) * 2 + f][nf] = __builtin_amdgcn_mfma_f32_16x16x32_bf16(\
                    AF[f][kk], bfr[nf][kk], acc[(Q) * 2 + f][nf], 0, 0, 0);   \
    __builtin_amdgcn_s_setprio(0);

#define WAITL()                                                               \
    asm volatile("s_waitcnt lgkmcnt(0)" ::: "memory");                        \
    __builtin_amdgcn_sched_barrier(0);

// One K-tile, 4 phases, 8 barriers, static slots (P = 0 or 2 literal).
#define KTILE(P, t)                                                           \
    {                                                                         \
        bf16x8 bfr[4][2], afA[2][2], afB[2][2];                               \
        const char* Ah = (const char*)&A_lds[(P) + wm][0];                    \
        const char* Bh = (const char*)&B_lds[(P) + (wn >> 1)][0];             \
        /* ph0: LDB(8) + LDA q0(4) | stage A0(t+1) */                         \
        LDB8(Bh)                                                              \
        LDA4(afA, Ah, 0)                                                      \
        if ((t) + 1 < NT) { STAGE(Ab + ((t) + 1) * BK, &A_lds[(P) ^ 2][0]) }  \
        bar(); WAITL()                                                        \
        MFMA16(afA, 0)                                                        \
        bar();                                                                \
        /* ph1: LDA q1 | stage A1(t+1) */                                     \
        LDA4(afB, Ah, 1)                                                      \
        if ((t) + 1 < NT) { STAGE(Ab + 128 * DIM + ((t) + 1) * BK,            \
                                  &A_lds[((P) ^ 2) + 1][0]) }                 \
        bar(); WAITL()                                                        \
        MFMA16(afB, 1)                                                        \
        bar();                                                                \
        /* ph2: LDA q2 | stage B0(t+2) (B[P] reads done in ph0) */            \
        LDA4(afA, Ah, 2)                                                      \
        if ((t) + 2 < NT) { STAGE(Bb + ((t) + 2) * BK, &B_lds[P][0]) }        \
        bar(); WAITL()                                                        \
        MFMA16(afA, 2)                                                        \
        bar();                                                                \
        /* ph3: LDA q3 | stage B1(t+2) | boundary counted vmcnt */            \
        LDA4(afB, Ah, 3)                                                      \
        if ((t) + 2 < NT) { STAGE(Bb + 128 * DIM + ((t) + 2) * BK,            \
                                  &B_lds[(P) + 1][0]) }                       \
        bar(); WAITL()                                                        \
        MFMA16(afB, 3)                                                        \
        if ((t) < NT - 2) { asm volatile("s_waitcnt vmcnt(4)" ::: "memory"); }\
        else              { asm volatile("s_waitcnt vmcnt(0)" ::: "memory"); }\
        bar();                                                                \
    }

    // prologue: A(0)->A[0],A[1]; B(0)->B[0],B[1]; B(1)->B[2],B[3].
    // 12 loads; vmcnt(4) -> A(0),B(0) landed, B(1) floats (forced by end-of-
    // t0's vmcnt(4) before its t=1 ph0 read).
    STAGE(Ab,                 &A_lds[0][0])
    STAGE(Ab + 128 * DIM,     &A_lds[1][0])
    STAGE(Bb,                 &B_lds[0][0])
    STAGE(Bb + 128 * DIM,     &B_lds[1][0])
    STAGE(Bb + BK,            &B_lds[2][0])
    STAGE(Bb + 128 * DIM + BK,&B_lds[3][0])
    asm volatile("s_waitcnt vmcnt(4)" ::: "memory");
    bar();

    for (int t = 0; t < NT; t += 2) {
        KTILE(0, t)
        KTILE(2, t + 1)
    }
#undef KTILE
#undef STAGE
#undef LDA4
#undef LDB8
#undef MFMA16
#undef WAITL

    // ---- epilogue: per-token (max, sumexp) over this block's 256 cols ----
    // C frag (verified): row = wm*128 + mf*16 + (lane>>4)*4 + r,
    // col = wn*64 + nf*16 + (lane&15). 16-wide shfl only (0-conflict).
    float* red_m = (float*)&A_lds[0][0];          // 4 KB
    float* red_s = ((float*)&A_lds[0][0]) + 1024; // 4 KB
    #pragma unroll
    for (int mf = 0; mf < 8; ++mf) {
        #pragma unroll
        for (int r = 0; r < 4; ++r) {
            float v0 = acc[mf][0][r], v1 = acc[mf][1][r];
            float v2 = acc[mf][2][r], v3 = acc[mf][3][r];
            float mx = fmaxf(fmaxf(v0, v1), fmaxf(v2, v3));
            #pragma unroll
            for (int msk = 1; msk < 16; msk <<= 1)
                mx = fmaxf(mx, __shfl_xor(mx, msk, 64));
            float se = __expf(v0 - mx) + __expf(v1 - mx) +
                       __expf(v2 - mx) + __expf(v3 - mx);
            #pragma unroll
            for (int msk = 1; msk < 16; msk <<= 1)
                se += __shfl_xor(se, msk, 64);
            if ((lane & 15) == 0) {
                const int row = wm * 128 + mf * 16 + (lane >> 4) * 4 + r;
                red_m[row * 4 + wn] = mx;
                red_s[row * 4 + wn] = se;
            }
        }
    }
    __syncthreads();
    if (tid < 256) {
        float M = red_m[tid * 4], S = red_s[tid * 4];
        #pragma unroll
        for (int j = 1; j < 4; ++j) {
            const float m2 = red_m[tid * 4 + j], s2 = red_s[tid * 4 + j];
            const float Mn = fmaxf(M, m2);
            S = S * __expf(M - Mn) + s2 * __expf(m2 - Mn);
            M = Mn;
        }
        part_m[(arow0 + tid) * NCH + chunk0 + voc_blk] = M;
        part_s[(arow0 + tid) * NCH + chunk0 + voc_blk] = S;
    }
}

// ------------------------------------------------------- exact label dot ----
__global__ __launch_bounds__(256) void label_dot(
    const float* __restrict__ h, const float* __restrict__ W,
    const void* __restrict__ labels, float* __restrict__ lab_logit)
{
    bool is64 = true;
    #pragma unroll
    for (int i = 0; i < 8; ++i) {
        long long v = ((const long long*)labels)[i];
        if (v < 0 || v >= VOCAB) is64 = false;
    }
    const int t = blockIdx.x;
    const int lab = is64 ? (int)((const long long*)labels)[t]
                         : ((const int*)labels)[t];
    const float4* hp = (const float4*)(h + (long)t * DIM);
    const float4* wp = (const float4*)(W + (long)lab * DIM);
    float s = 0.f;
    #pragma unroll
    for (int j = 0; j < 2; ++j) {
        const float4 a = hp[threadIdx.x + j * 256];
        const float4 b = wp[threadIdx.x + j * 256];
        s += a.x * b.x + a.y * b.y + a.z * b.z + a.w * b.w;
    }
    #pragma unroll
    for (int msk = 1; msk < 64; msk <<= 1) s += __shfl_xor(s, msk, 64);
    __shared__ float ps[4];
    if ((threadIdx.x & 63) == 0) ps[threadIdx.x >> 6] = s;
    __syncthreads();
    if (threadIdx.x == 0) lab_logit[t] = ps[0] + ps[1] + ps[2] + ps[3];
}

// ---------------------------------------------------- per-token LSE merge ---
__global__ __launch_bounds__(256) void finalize_nll(
    const float* __restrict__ part_m, const float* __restrict__ part_s,
    const float* __restrict__ lab_logit, const float* __restrict__ wts,
    float* __restrict__ wnll)
{
    const int t    = blockIdx.x * 4 + (threadIdx.x >> 6);  // one wave / token
    const int lane = threadIdx.x & 63;
    float m = -3.4e38f, s = 0.f;
    #pragma unroll
    for (int j = 0; j < 4; ++j) {
        const int c = j * 64 + lane;
        const float pm = part_m[(long)t * NCH + c];
        const float ps = part_s[(long)t * NCH + c];
        const float M = fmaxf(m, pm);
        s = s * __expf(m - M) + ps * __expf(pm - M);
        m = M;
    }
    #pragma unroll
    for (int msk = 1; msk < 64; msk <<= 1) {
        const float om = __shfl_xor(m, msk, 64);
        const float os = __shfl_xor(s, msk, 64);
        const float M = fmaxf(m, om);
        s = s * __expf(m - M) + os * __expf(om - M);
        m = M;
    }
    if (lane == 0) {
        const float lse = m + logf(s);
        wnll[t] = wts[t] * (lse - lab_logit[t]);
    }
}

// -------------------------------------------------- deterministic reduce ----
__global__ __launch_bounds__(1024) void final_reduce(
    const float* __restrict__ wnll, const float* __restrict__ wts,
    float* __restrict__ out)
{
    float a = 0.f, b = 0.f;
    #pragma unroll
    for (int j = 0; j < 4; ++j) {
        const int i = threadIdx.x + j * 1024;
        a += wnll[i];
        b += wts[i];
    }
    #pragma unroll
    for (int msk = 1; msk < 64; msk <<= 1) {
        a += __shfl_xor(a, msk, 64);
        b += __shfl_xor(b, msk, 64);
    }
    __shared__ float pa[16], pb[16];
    if ((threadIdx.x & 63) == 0) {
        pa[threadIdx.x >> 6] = a;
        pb[threadIdx.x >> 6] = b;
    }
    __syncthreads();
    if (threadIdx.x == 0) {
        float A = 0.f, B = 0.f;
        #pragma unroll
        for (int i = 0; i < 16; ++i) { A += pa[i]; B += pb[i]; }
        out[0] = A / B;
    }
}

// ----------------------------------------------------------------- launch ---
extern "C" void kernel_launch(void* const* d_in, const int* in_sizes, int n_in,
                              void* d_out, int out_size, void* d_ws, size_t ws_size,
                              hipStream_t stream)
{
    const float* h      = (const float*)d_in[0];
    const void*  labels = d_in[1];
    const float* wts    = (const float*)d_in[2];
    const float* W      = (const float*)d_in[3];
    float* out = (float*)d_out;

    char* ws = (char*)d_ws;
    unsigned short* h_bf      = (unsigned short*)(ws);                 // 16 MB
    float*          part_m    = (float*)(ws + (16u << 20));            //  4 MB
    float*          part_s    = (float*)(ws + (24u << 20));            //  4 MB
    float*          lab_logit = (float*)(ws + (32u << 20));            // 16 KB
    float*          wnll      = (float*)(ws + (32u << 20) + 16384);    // 16 KB
    unsigned short* wseg      = (unsigned short*)(ws + (32u << 20) + 32768);
    const size_t base = (size_t)(32u << 20) + 32768;

    long segmax = 0;
    if (ws_size > base) segmax = (long)((ws_size - base) / ((size_t)DIM * 2));
    segmax &= ~255L;
    if (segmax > VOCAB) segmax = VOCAB;
    if (segmax < 256)   segmax = 256;   // require ws_size >= ~34 MB

    // 0) h -> bf16
    convert_f32_bf16<<<(N_TOK * DIM) / (256 * 8), 256, 0, stream>>>(
        h, h_bf, (long)N_TOK * DIM);

    // 1) segmented W conversion + fused GEMM/LSE partials
    for (long v0 = 0; v0 < VOCAB; v0 += segmax) {
        const long rows = (VOCAB - v0) < segmax ? (VOCAB - v0) : segmax;
        convert_f32_bf16<<<(int)(rows * DIM / (256 * 8)), 256, 0, stream>>>(
            W + v0 * DIM, wseg, rows * (long)DIM);
        const int nwg = (int)(rows / BM) * NTB;
        gemm_lse<<<nwg, 512, 0, stream>>>(h_bf, wseg, part_m, part_s,
                                          (int)(v0 / BN));
    }

    // 2) exact label logits (fp32)
    label_dot<<<N_TOK, 256, 0, stream>>>(h, W, labels, lab_logit);

    // 3) per-token LSE merge -> w*nll
    finalize_nll<<<N_TOK / 4, 256, 0, stream>>>(part_m, part_s, lab_logit,
                                                wts, wnll);

    // 4) weighted mean
    final_reduce<<<1, 1024, 0, stream>>>(wnll, wts, out);
}